// Round 10
// baseline (43.002 us; speedup 1.0000x reference)
//
#include <hip/hip_runtime.h>
#include <math.h>

// Kaldi LinearResample 16000 -> 22050, LPW=6.
// P=441 phases, STRIDE=320, W=13 taps, tot = 441*3000.
// R10: SINGLE fused kernel.
//   - per-block weight table (441 phases x 20 padded taps) built in LDS with
//     exact-integer f32 math (R9-verified: num = ii*22050 - p*16000 exact;
//     |num|<=133636 <=> inside window), ~20 sinf/cosf per thread, 1 barrier;
//   - then R3's champion compute shape: thread (g=t%147, third=t/147) holds
//     15 float4 weights in registers, gathers one aligned 20-float window
//     (5x float4) per m-step DIRECTLY from global (L2-resident input), 3
//     outputs x 8 m-steps, plain dwordx3 stores (L2 write-back coalesces;
//     R7 lesson: no nontemporal partial-line stores).
//   - edge guards hoisted to block level: only mc==0 / mc==124 guarded.
// Kills: table kernel launch + serialization + global weight traffic.
#define P      441
#define STRIDE 320
#define GPW    3
#define NG     147         // 441/3
#define W20    20
#define MBLK   24          // m per block
#define MCH    125         // 3000/MBLK
#define BATCH  8
#define NW     (P * W20)   // 8820 weights, 35.3 KB LDS

#ifndef M_PI
#define M_PI 3.14159265358979323846
#endif

// fi[p] = ceil(p*320/441 - 6.060606..) exactly, via integer math.
__device__ __forceinline__ int kaldi_fi_int(int p) {
    int q = (p * 320) / 441;
    int r = p * 320 - q * 441;
    return q - 6 + (r <= 26 ? 0 : 1);
}

// Weight for slot j of phase p, window base ab (= fi[3*(p/3)] & ~3).
// dt = (ab+j)/16000 - p/22050 = num/352800000 with num exact in int32.
__device__ __forceinline__ float kaldi_w(int p, int ab, int j) {
    int num = (ab + j) * 22050 - p * 16000;
    float wf = 0.f;
    if (num == 0) {
        wf = 0.99f;                                  // 2*cutoff/ORIG
    } else if (num <= 133636 && num >= -133636) {    // |dt| < ww exactly
        float nf = (float)num;
        float hann = 0.5f + 0.5f * __cosf(nf * (float)(2.0 * M_PI * 1320.0 / 352800000.0));
        float s = __sinf(nf * (float)(2.0 * M_PI * 7920.0 / 352800000.0));
        // 1/(pi*dt*16000) = (22050/pi)/num
        wf = hann * s * (float)(22050.0 / M_PI) * __builtin_amdgcn_rcpf(nf);
    }
    return wf;
}

// 5 independent 4-FMA chains + add tree (no serial 19-add chain).
__device__ __forceinline__ float dot20f(const float4& x0, const float4& x1,
                                        const float4& x2, const float4& x3,
                                        const float4& x4, const float4* w) {
    float p0 = x0.x * w[0].x;
    p0 = fmaf(x0.y, w[0].y, p0); p0 = fmaf(x0.z, w[0].z, p0); p0 = fmaf(x0.w, w[0].w, p0);
    float p1 = x1.x * w[1].x;
    p1 = fmaf(x1.y, w[1].y, p1); p1 = fmaf(x1.z, w[1].z, p1); p1 = fmaf(x1.w, w[1].w, p1);
    float p2 = x2.x * w[2].x;
    p2 = fmaf(x2.y, w[2].y, p2); p2 = fmaf(x2.z, w[2].z, p2); p2 = fmaf(x2.w, w[2].w, p2);
    float p3 = x3.x * w[3].x;
    p3 = fmaf(x3.y, w[3].y, p3); p3 = fmaf(x3.z, w[3].z, p3); p3 = fmaf(x3.w, w[3].w, p3);
    float p4 = x4.x * w[4].x;
    p4 = fmaf(x4.y, w[4].y, p4); p4 = fmaf(x4.z, w[4].z, p4); p4 = fmaf(x4.w, w[4].w, p4);
    return ((p0 + p1) + (p2 + p3)) + p4;
}

__global__ __launch_bounds__(448) void resample10_kernel(
    const float* __restrict__ x, float* __restrict__ out, int n, int tot)
{
    __shared__ float sw[NW];

    const int b  = blockIdx.y;
    const int mc = blockIdx.x;

    // ---- build the weight table in LDS (all 448 threads, ~20 weights each) ----
    for (int i = threadIdx.x; i < NW; i += 448) {
        int p = i / W20;
        int j = i - p * W20;
        int g3 = p - (p % GPW);                  // first phase of p's group
        int ab = kaldi_fi_int(g3) & ~3;
        sw[i] = kaldi_w(p, ab, j);
    }
    __syncthreads();

    const int t = threadIdx.x;
    if (t >= P) return;
    const int g     = t % NG;                    // phase group
    const int third = t / NG;                    // 8-m slice
    const int ab = kaldi_fi_int(GPW * g) & ~3;

    float4 w[15];
    const float4* wp = (const float4*)(sw + g * (GPW * W20));
    #pragma unroll
    for (int i = 0; i < 15; ++i) w[i] = wp[i];

    const float* __restrict__ xb = x + (size_t)b * n;
    float* __restrict__ ob = out + (size_t)b * tot;

    const int m0 = mc * MBLK + third * 8;
    int base = ab + m0 * STRIDE;
    int tout = m0 * P + GPW * g;

    if (mc != 0 && mc != MCH - 1) {
        // Interior: all windows in-bounds; branch-free.
        #pragma unroll 2
        for (int k = 0; k < 8; ++k) {
            const float4* q4 = (const float4*)(xb + base);
            float4 x0 = q4[0], x1 = q4[1], x2 = q4[2], x3 = q4[3], x4 = q4[4];
            float a0 = dot20f(x0, x1, x2, x3, x4, &w[0]);
            float a1 = dot20f(x0, x1, x2, x3, x4, &w[5]);
            float a2 = dot20f(x0, x1, x2, x3, x4, &w[10]);
            ob[tout]     = a0;                   // merges to dwordx3
            ob[tout + 1] = a1;
            ob[tout + 2] = a2;
            base += STRIDE; tout += P;
        }
    } else {
        // Edge blocks (16 of 1000): guard each window.
        const unsigned slim = (unsigned)(n - W20);
        for (int k = 0; k < 8; ++k) {
            float4 x0, x1, x2, x3, x4;
            if ((unsigned)base <= slim) {
                const float4* q4 = (const float4*)(xb + base);
                x0 = q4[0]; x1 = q4[1]; x2 = q4[2]; x3 = q4[3]; x4 = q4[4];
            } else {
                float xs[W20];
                #pragma unroll
                for (int j = 0; j < W20; ++j) {
                    int ii = base + j;
                    xs[j] = (ii >= 0 && ii < n) ? xb[ii] : 0.f;
                }
                x0 = make_float4(xs[0], xs[1], xs[2], xs[3]);
                x1 = make_float4(xs[4], xs[5], xs[6], xs[7]);
                x2 = make_float4(xs[8], xs[9], xs[10], xs[11]);
                x3 = make_float4(xs[12], xs[13], xs[14], xs[15]);
                x4 = make_float4(xs[16], xs[17], xs[18], xs[19]);
            }
            float a0 = dot20f(x0, x1, x2, x3, x4, &w[0]);
            float a1 = dot20f(x0, x1, x2, x3, x4, &w[5]);
            float a2 = dot20f(x0, x1, x2, x3, x4, &w[10]);
            ob[tout]     = a0;
            ob[tout + 1] = a1;
            ob[tout + 2] = a2;
            base += STRIDE; tout += P;
        }
    }
}

extern "C" void kernel_launch(void* const* d_in, const int* in_sizes, int n_in,
                              void* d_out, int out_size, void* d_ws, size_t ws_size,
                              hipStream_t stream) {
    const float* x = (const float*)d_in[0];
    float* out = (float*)d_out;

    const int n = in_sizes[0] / BATCH;     // 960000

    // Kaldi GetNumOutputSamples
    long long interval = (long long)n * P;
    long long last = interval / STRIDE;
    if (last * STRIDE == interval) last -= 1;
    const int tot = (int)(last + 1);       // 1,323,000 = 441*3000

    dim3 grid(MCH, BATCH);                 // 125 x 8 = 1000 blocks, ONE kernel
    resample10_kernel<<<grid, 448, 0, stream>>>(x, out, n, tot);
}

// Round 11
// 32.583 us; speedup vs baseline: 1.3198x; 1.3198x over previous
//
#include <hip/hip_runtime.h>
#include <math.h>

// Kaldi LinearResample 16000 -> 22050, LPW=6.
// P=441 phases, STRIDE=320, W=13 taps, tot = 441*3000.
// R11 = R3 champion structure (split table kernel + direct global gather,
// 15 float4 weights in registers, 3 outputs x MPT m-steps, per-iter guard,
// unroll 2, scalar NT stores) with TWO targeted changes:
//   - MPT 12 -> 6 (588K threads, 2297 blocks): R2/R3 ran only ~18 waves/CU
//     (grid-limited, occupancy 48.6%) and the kernel is latency-bound ->
//     double the resident-wave supply. R10's fusion lesson: keep the sinf
//     table OUT of the hot kernel (it cost 124 VGPR -> 14.8% occupancy).
//   - table built by the R9-verified exact-integer f32 kernel (absmax 0.0156,
//     threshold 0.1025) instead of f64 sincos: kills the serialized tail.
#define P      441
#define STRIDE 320
#define GPW    3
#define NG     147         // 441/3
#define W20    20
#define MPT    6           // m-steps per thread
#define MCH    500         // 3000/MPT
#define BATCH  8

#ifndef M_PI
#define M_PI 3.14159265358979323846
#endif

// fi[p] = ceil(p*320/441 - 6.060606..) exactly, via integer math.
__device__ __forceinline__ int kaldi_fi_int(int p) {
    int q = (p * 320) / 441;
    int r = p * 320 - q * 441;
    return q - 6 + (r <= 26 ? 0 : 1);
}

// One thread per (phase, slot j in [0,20)): w20[p][j] = weight applied to
// x[gab[p/3] + j]; slots outside the 13-tap support are exactly 0 (|num|
// test is exact integer). gab[g] = fi[3g] & ~3.
__global__ void build_table20_f32(float* __restrict__ w20, int* __restrict__ gab) {
    int idx = blockIdx.x * blockDim.x + threadIdx.x;
    if (idx >= P * W20) return;
    int p = idx / W20;
    int j = idx - p * W20;
    int ab = kaldi_fi_int(p - (p % GPW)) & ~3;
    if (j == 0 && (p % GPW) == 0) gab[p / GPW] = ab;
    // dt = (ab+j)/16000 - p/22050 = num / 352800000, num exact in int32
    int num = (ab + j) * 22050 - p * 16000;
    float wf = 0.f;
    if (num == 0) {
        wf = 0.99f;                                    // 2*cutoff/ORIG
    } else if (num <= 133636 && num >= -133636) {      // |dt| < ww exactly
        float dt = (float)num * (1.0f / 352800000.0f);
        float hann = 0.5f + 0.5f * __cosf(2.0f * (float)M_PI * 1320.0f * dt);
        float s = __sinf(2.0f * (float)M_PI * 7920.0f * dt);
        wf = hann * s / ((float)M_PI * dt) * (1.0f / 16000.0f);
    }
    w20[idx] = wf;
}

// 5 independent 4-FMA chains + add tree.
__device__ __forceinline__ float dot20f(const float4& x0, const float4& x1,
                                        const float4& x2, const float4& x3,
                                        const float4& x4, const float4* w) {
    float p0 = x0.x * w[0].x;
    p0 = fmaf(x0.y, w[0].y, p0); p0 = fmaf(x0.z, w[0].z, p0); p0 = fmaf(x0.w, w[0].w, p0);
    float p1 = x1.x * w[1].x;
    p1 = fmaf(x1.y, w[1].y, p1); p1 = fmaf(x1.z, w[1].z, p1); p1 = fmaf(x1.w, w[1].w, p1);
    float p2 = x2.x * w[2].x;
    p2 = fmaf(x2.y, w[2].y, p2); p2 = fmaf(x2.z, w[2].z, p2); p2 = fmaf(x2.w, w[2].w, p2);
    float p3 = x3.x * w[3].x;
    p3 = fmaf(x3.y, w[3].y, p3); p3 = fmaf(x3.z, w[3].z, p3); p3 = fmaf(x3.w, w[3].w, p3);
    float p4 = x4.x * w[4].x;
    p4 = fmaf(x4.y, w[4].y, p4); p4 = fmaf(x4.z, w[4].z, p4); p4 = fmaf(x4.w, w[4].w, p4);
    return ((p0 + p1) + (p2 + p3)) + p4;
}

// Thread owns (b, mc, g): GPW=3 outputs x MPT=6 m-steps.
// Lanes = consecutive g -> overlapping loads, dense dwordx3 stores.
__global__ __launch_bounds__(256) void resample11_kernel(
    const float* __restrict__ x, const float* __restrict__ w20,
    const int* __restrict__ gab, float* __restrict__ out,
    int n, int tot)
{
    int tid = blockIdx.x * blockDim.x + threadIdx.x;
    if (tid >= BATCH * MCH * NG) return;   // 588,000
    int g    = tid % NG;
    int rest = tid / NG;
    int mc   = rest % MCH;
    int b    = rest / MCH;

    const float* __restrict__ xb = x + (size_t)b * n;
    float* __restrict__ ob = out + (size_t)b * tot;

    const float4* wp = (const float4*)(w20 + g * (GPW * W20));
    float4 w[15];
    #pragma unroll
    for (int i = 0; i < 15; ++i) w[i] = wp[i];

    const int ab = gab[g];
    int base = ab + mc * MPT * STRIDE;
    int t    = mc * MPT * P + g * GPW;

    #pragma unroll 2
    for (int k = 0; k < MPT; ++k) {
        float4 x0, x1, x2, x3, x4;
        if (base >= 0 && base + W20 <= n) {
            const float4* q = (const float4*)(xb + base);
            x0 = q[0]; x1 = q[1]; x2 = q[2]; x3 = q[3]; x4 = q[4];
        } else {
            float xs[W20];
            #pragma unroll
            for (int j = 0; j < W20; ++j) {
                int ii = base + j;
                xs[j] = (ii >= 0 && ii < n) ? xb[ii] : 0.f;
            }
            x0 = make_float4(xs[0], xs[1], xs[2], xs[3]);
            x1 = make_float4(xs[4], xs[5], xs[6], xs[7]);
            x2 = make_float4(xs[8], xs[9], xs[10], xs[11]);
            x3 = make_float4(xs[12], xs[13], xs[14], xs[15]);
            x4 = make_float4(xs[16], xs[17], xs[18], xs[19]);
        }
        float a0 = dot20f(x0, x1, x2, x3, x4, &w[0]);
        float a1 = dot20f(x0, x1, x2, x3, x4, &w[5]);
        float a2 = dot20f(x0, x1, x2, x3, x4, &w[10]);
        __builtin_nontemporal_store(a0, &ob[t]);
        __builtin_nontemporal_store(a1, &ob[t + 1]);
        __builtin_nontemporal_store(a2, &ob[t + 2]);
        base += STRIDE; t += P;
    }
}

extern "C" void kernel_launch(void* const* d_in, const int* in_sizes, int n_in,
                              void* d_out, int out_size, void* d_ws, size_t ws_size,
                              hipStream_t stream) {
    const float* x = (const float*)d_in[0];
    float* out = (float*)d_out;

    const int n = in_sizes[0] / BATCH;     // 960000

    // Kaldi GetNumOutputSamples
    long long interval = (long long)n * P;
    long long last = interval / STRIDE;
    if (last * STRIDE == interval) last -= 1;
    const int tot = (int)(last + 1);       // 1,323,000 = 441*3000

    float* w20 = (float*)d_ws;
    int*   gab = (int*)((char*)d_ws + (size_t)P * W20 * sizeof(float));

    build_table20_f32<<<(P * W20 + 255) / 256, 256, 0, stream>>>(w20, gab);

    const int nthreads = BATCH * MCH * NG;        // 588,000
    const int nblk = (nthreads + 255) / 256;      // 2297
    resample11_kernel<<<nblk, 256, 0, stream>>>(x, w20, gab, out, n, tot);
}